// Round 11
// baseline (236.310 us; speedup 1.0000x reference)
//
#include <hip/hip_runtime.h>
#include <hip/hip_bf16.h>
#include <hip/hip_fp16.h>
#include <math.h>

#define NN 50000
#define EE 800000
#define DIN 128
#define HEADS 8
#define DH 16
#define DOUT 16
#define NEG 0.2f
#define GM 32       // nodes per GEMM block
#define GB ((NN + GM - 1) / GM)     // 1563 gemm1 blocks
#define NB ((NN + 255) / 256)       // 196 cnt-init blocks
#define ABLK ((EE / 4 + 255) / 256) // 782 bucket-append blocks
#define NPART 8                     // one dst-range per XCD (blockIdx%8 ~ XCD round-robin)
#define RANGE (NN / NPART)          // 6250 dst nodes per range
#define RB 1563                     // blocks per range in l1/l2 (ceil(RANGE/4))
#define SCATB 64                    // blocks per range in scatter kernel
#define BUCKCAP 110000              // per-range bucket capacity (mean 100k, sigma~296)
#define PAD 64      // padded CSR row slots; deg ~ Poisson(16), P(deg>=64) ~ 2e-18/node

typedef __attribute__((ext_vector_type(8))) short bf16x8;
typedef __attribute__((ext_vector_type(4))) float f32x4;
typedef __attribute__((ext_vector_type(4))) int i32x4;

__device__ __forceinline__ unsigned pack2bf(float a, float b) {
    union { __hip_bfloat162 h; unsigned u; } c;
    c.h = __float22bfloat162_rn(make_float2(a, b));
    return c.u;
}
__device__ __forceinline__ unsigned short f2bf(float v) {
    union { __hip_bfloat16 h; unsigned short u; } c;
    c.h = __float2bfloat16(v);
    return c.u;
}
__device__ __forceinline__ unsigned short f2h(float v) {
    union { __half h; unsigned short u; } c;
    c.h = __float2half(v);
    return c.u;
}
__device__ __forceinline__ float bflo(unsigned u) { return __uint_as_float(u << 16); }
__device__ __forceinline__ float bfhi(unsigned u) { return __uint_as_float(u & 0xffff0000u); }
__device__ __forceinline__ float h2lo(unsigned u) {
    union { unsigned short s; __half h; } c; c.s = (unsigned short)(u & 0xffffu);
    return __half2float(c.h);
}
__device__ __forceinline__ float h2hi(unsigned u) {
    union { unsigned short s; __half h; } c; c.s = (unsigned short)(u >> 16);
    return __half2float(c.h);
}
// ELU negative branch: __expf(x)-1 (2 instr) instead of libm expm1f (~30 instr).
__device__ __forceinline__ float elu1(float x) { return x > 0.f ? x : __expf(x) - 1.f; }

// ---------- k0: weight conversion only (tiny, unblocks gemm1 in kA) ----------
__global__ __launch_bounds__(256) void wcvt(const float* __restrict__ Wl,
                                            const float* __restrict__ Wr,
                                            unsigned short* __restrict__ Wb,
                                            const float* __restrict__ Wl2,
                                            const float* __restrict__ Wr2,
                                            unsigned short* __restrict__ Wb2) {
    int b = blockIdx.x, t = threadIdx.x;
    if (b < 128) {
        int i = b * 256 + t;          // 32768 entries: Wb[n][k]
        int n = i >> 7, k = i & 127;
        float v = (n < 128) ? Wl[k * 128 + n] : Wr[k * 128 + (n - 128)];
        Wb[i] = f2bf(v);
    } else {
        int i = (b - 128) * 256 + t;  // 4096 entries: Wb2[n][k], n in [0,32)
        int n = i >> 7, k = i & 127;
        float v = (n < 16) ? Wl2[k * 16 + n] : Wr2[k * 16 + (n - 16)];
        Wb2[i] = f2bf(v);
    }
}

// ---------- kA: cnt-init (0..NB) || bucket append (NB..NB+ABLK) || gemm1 MFMA (rest) ----------
// KEY CHANGE (this round): bucket sort co-runs with gemm1's dense MFMA stream instead of
// running alone in its own kernel — the bucket's latency-bound blocks are backfilled.
// bhead zeroed by hipMemsetAsync before this kernel. Bucket LDS scratch aliases As/Cs.
__global__ __launch_bounds__(256) void bucket_gemm1(int* __restrict__ cnt,
                                                    const int* __restrict__ ei,
                                                    unsigned* __restrict__ bhead,
                                                    unsigned* __restrict__ bucket,
                                                    const float* __restrict__ x,
                                                    const unsigned short* __restrict__ Wb,
                                                    unsigned short* __restrict__ xlb,
                                                    unsigned short* __restrict__ xr) {
    __shared__ unsigned short As[GM][136];   // gemm1 staging | bucket lrec alias (4KB<8.7KB)
    __shared__ unsigned short Cs[GM][264];   // gemm1 C transpose | bucket counters alias
    int t = threadIdx.x;
    if (blockIdx.x < NB) {          // ---- cnt init ----
        int i = blockIdx.x * 256 + t;
        if (i < NN) cnt[i] = 1;     // slot 0 = self-loop (written in scatter kernel)
        return;
    }
    if (blockIdx.x < NB + ABLK) {   // ---- bucket append: LDS 8-way sort, coalesced out ----
        unsigned* lrec = (unsigned*)&As[0][0];    // 1024 u32
        unsigned* lcnt = (unsigned*)&Cs[0][0];    // 8
        unsigned* loff = lcnt + 8;
        unsigned* lpos = loff + 8;
        unsigned* gbase = lpos + 8;
        int ab = blockIdx.x - NB;
        int i = ab * 256 + t;
        bool valid = i < EE / 4;
        i32x4 ss, dd;
        unsigned bb[4];
        if (valid) {
            ss = __builtin_nontemporal_load(((const i32x4*)ei) + i);
            dd = __builtin_nontemporal_load(((const i32x4*)(ei + EE)) + i);
        }
        if (t < 8) { lcnt[t] = 0; lpos[t] = 0; }
        __syncthreads();
        if (valid) {
#pragma unroll
            for (int e = 0; e < 4; ++e) {
                bb[e] = (unsigned)dd[e] / RANGE;
                atomicAdd(&lcnt[bb[e]], 1u);
            }
        }
        __syncthreads();
        if (t == 0) {
            unsigned run = 0;
#pragma unroll
            for (int q = 0; q < 8; ++q) { loff[q] = run; run += lcnt[q]; }
        }
        if (t < 8 && lcnt[t] > 0) gbase[t] = atomicAdd(&bhead[t], lcnt[t]);
        __syncthreads();
        if (valid) {
#pragma unroll
            for (int e = 0; e < 4; ++e) {
                unsigned p = atomicAdd(&lpos[bb[e]], 1u);
                lrec[loff[bb[e]] + p] = ((unsigned)ss[e] << 16) | (unsigned)dd[e];
            }
        }
        __syncthreads();
        unsigned total = loff[7] + lcnt[7];
        for (unsigned j = t; j < total; j += 256) {
            unsigned q = 0;
            while (q < 7 && j >= loff[q + 1]) ++q;
            bucket[(size_t)q * BUCKCAP + gbase[q] + (j - loff[q])] = lrec[j];
        }
        return;
    }
    // ---- gemm1 path: 32 nodes x 256 cols, 4 waves; m89-verified 16x16x32 bf16 layouts ----
    int n0 = (blockIdx.x - (NB + ABLK)) * GM;
    {   // stage: 32 rows x 128 ch fp32 -> bf16 LDS (nt: x is read-once)
        int row = t >> 3, seg = t & 7;
        int nsrc = n0 + row < NN ? n0 + row : NN - 1;   // clamp: safe read, store guarded
        const f32x4* xp = (const f32x4*)(x + (size_t)nsrc * DIN + 16 * seg);
        f32x4 v0 = __builtin_nontemporal_load(xp);
        f32x4 v1 = __builtin_nontemporal_load(xp + 1);
        f32x4 v2 = __builtin_nontemporal_load(xp + 2);
        f32x4 v3 = __builtin_nontemporal_load(xp + 3);
        uint4 p0 = make_uint4(pack2bf(v0[0], v0[1]), pack2bf(v0[2], v0[3]),
                              pack2bf(v1[0], v1[1]), pack2bf(v1[2], v1[3]));
        uint4 p1 = make_uint4(pack2bf(v2[0], v2[1]), pack2bf(v2[2], v2[3]),
                              pack2bf(v3[0], v3[1]), pack2bf(v3[2], v3[3]));
        *(uint4*)&As[row][16 * seg]     = p0;
        *(uint4*)&As[row][16 * seg + 8] = p1;
    }
    __syncthreads();
    int lane = t & 63, w = t >> 6;
    int m = lane & 15, quad = lane >> 4;
    f32x4 acc[2][4];
#pragma unroll
    for (int mt = 0; mt < 2; ++mt)
#pragma unroll
        for (int nt = 0; nt < 4; ++nt) acc[mt][nt] = (f32x4){0.f, 0.f, 0.f, 0.f};
#pragma unroll
    for (int ks = 0; ks < 4; ++ks) {
        int k = 32 * ks + 8 * quad;
        bf16x8 a0 = *(const bf16x8*)&As[m][k];
        bf16x8 a1 = *(const bf16x8*)&As[16 + m][k];
#pragma unroll
        for (int nt = 0; nt < 4; ++nt) {
            int n = 64 * w + 16 * nt + m;
            bf16x8 b = *(const bf16x8*)(Wb + (size_t)n * 128 + k);
            acc[0][nt] = __builtin_amdgcn_mfma_f32_16x16x32_bf16(a0, b, acc[0][nt], 0, 0, 0);
            acc[1][nt] = __builtin_amdgcn_mfma_f32_16x16x32_bf16(a1, b, acc[1][nt], 0, 0, 0);
        }
    }
    // C -> LDS transpose tile: bf16 for cols [0,128) (xlb), fp16 for [128,256) (xr)
#pragma unroll
    for (int mt = 0; mt < 2; ++mt) {
#pragma unroll
        for (int nt = 0; nt < 4; ++nt) {
            int col = 64 * w + 16 * nt + m;
            int rbase = 16 * mt + 4 * quad;
            if (col < 128) {
#pragma unroll
                for (int r = 0; r < 4; ++r) Cs[rbase + r][col] = f2bf(acc[mt][nt][r]);
            } else {
#pragma unroll
                for (int r = 0; r < 4; ++r) Cs[rbase + r][col] = f2h(acc[mt][nt][r]);
            }
        }
    }
    __syncthreads();
    {   // coalesced write-out: thread (row, seg) moves 32B to xlb and 32B to xr
        int row = t >> 3, seg = t & 7;
        int grow = n0 + row;
        if (grow < NN) {
            uint4 a0 = *(uint4*)&Cs[row][16 * seg];
            uint4 a1 = *(uint4*)&Cs[row][16 * seg + 8];
            *(uint4*)(xlb + (unsigned)grow * DIN + 16 * seg)     = a0;
            *(uint4*)(xlb + (unsigned)grow * DIN + 16 * seg + 8) = a1;
            uint4 b0 = *(uint4*)&Cs[row][128 + 16 * seg];
            uint4 b1 = *(uint4*)&Cs[row][128 + 16 * seg + 8];
            *(uint4*)(xr + (unsigned)grow * DIN + 16 * seg)     = b0;
            *(uint4*)(xr + (unsigned)grow * DIN + 16 * seg + 8) = b1;
        }
    }
}

// ---------- kB: scatter alone: L2-resident per-XCD CSR build (no competing stream) ----------
__global__ __launch_bounds__(256) void scatter_b(const unsigned* __restrict__ bucket,
                                                 const unsigned* __restrict__ bhead,
                                                 int* __restrict__ cnt,
                                                 unsigned short* __restrict__ esrcPad) {
    int r = blockIdx.x & 7;
    int g = blockIdx.x >> 3;        // 0..SCATB-1
    int t = threadIdx.x;
    if (g == 0) {                   // self-loops for this range
        for (int dq = t; dq < RANGE; dq += 256) {
            int d = r * RANGE + dq;
            esrcPad[(unsigned)d * PAD] = (unsigned short)d;
        }
    }
    unsigned n = bhead[r];
    for (unsigned i = (unsigned)g * 256 + t; i < n; i += SCATB * 256) {
        unsigned rec = __builtin_nontemporal_load(bucket + (size_t)r * BUCKCAP + i);
        unsigned s = rec >> 16, d = rec & 0xffffu;
        int p = atomicAdd(&cnt[d], 1);
        esrcPad[d * PAD + p] = (unsigned short)s;
    }
}

// ---------- k3: layer-1 fused: logits + segment softmax + gather + bias + ELU -> bf16 hb ----------
// one wave per dst; quarter-wave per edge slot: 16 lanes x 8 bf16 channels.
// Range r = blockIdx&7 (XCD-aligned with scatter). 32-bit addressing in hot loop.
__global__ __launch_bounds__(256) void l1_fused(const unsigned short* __restrict__ esrcPad,
                                                const int* __restrict__ cnt,
                                                const unsigned short* __restrict__ xlb,
                                                const unsigned short* __restrict__ xr,
                                                const float* __restrict__ att,
                                                const float* __restrict__ bias,
                                                unsigned short* __restrict__ hb) {
    int r = blockIdx.x & 7;
    int dq = (blockIdx.x >> 3) * 4 + (threadIdx.x >> 6);
    if (dq >= RANGE) return;        // wave-uniform (last block of each range)
    int d = r * RANGE + dq;
    int lane = threadIdx.x & 63;
    int quarter = lane >> 4;
    int q16 = lane & 15;        // channel octet [8*q16, 8*q16+8)
    int rs = d * PAD;
    int re = rs + cnt[d];       // cnt >= 1 (self-loop)
    int last = re - 1;
    uint4 xru = ((const uint4*)(xr + (unsigned)d * DIN))[q16];  // 8 fp16 ch
    float4 xr0, xr1;
    xr0.x = h2lo(xru.x); xr0.y = h2hi(xru.x);
    xr0.z = h2lo(xru.y); xr0.w = h2hi(xru.y);
    xr1.x = h2lo(xru.z); xr1.y = h2hi(xru.z);
    xr1.z = h2lo(xru.w); xr1.w = h2hi(xru.w);
    float4 at0 = ((const float4*)att)[2 * q16];
    float4 at1 = ((const float4*)att)[2 * q16 + 1];
    float4 a0 = make_float4(0.f, 0.f, 0.f, 0.f);
    float4 a1 = make_float4(0.f, 0.f, 0.f, 0.f);
    float l = 0.f;
    int slot = rs + quarter;
    int c0 = slot < last ? slot : last;
    unsigned s0 = esrcPad[c0];
    int c1 = slot + 4 < last ? slot + 4 : last;
    unsigned s1 = esrcPad[c1];
    uint4 row = ((const uint4*)(xlb + s0 * (unsigned)DIN))[q16];
    for (; slot < re; slot += 4) {
        uint4 cur = row;
        int c2 = slot + 8 < last ? slot + 8 : last;
        unsigned s2 = esrcPad[c2];                                 // 2 ahead
        row = ((const uint4*)(xlb + s1 * (unsigned)DIN))[q16];     // 1 ahead
        s1 = s2;
        float f0 = bflo(cur.x), f1 = bfhi(cur.x);
        float f2 = bflo(cur.y), f3 = bfhi(cur.y);
        float f4 = bflo(cur.z), f5 = bfhi(cur.z);
        float f6 = bflo(cur.w), f7 = bfhi(cur.w);
        float v0 = f0 + xr0.x; v0 = fmaxf(v0, NEG * v0);
        float v1 = f1 + xr0.y; v1 = fmaxf(v1, NEG * v1);
        float v2 = f2 + xr0.z; v2 = fmaxf(v2, NEG * v2);
        float v3 = f3 + xr0.w; v3 = fmaxf(v3, NEG * v3);
        float v4 = f4 + xr1.x; v4 = fmaxf(v4, NEG * v4);
        float v5 = f5 + xr1.y; v5 = fmaxf(v5, NEG * v5);
        float v6 = f6 + xr1.z; v6 = fmaxf(v6, NEG * v6);
        float v7 = f7 + xr1.w; v7 = fmaxf(v7, NEG * v7);
        float w = at0.x * v0 + at0.y * v1 + at0.z * v2 + at0.w * v3
                + at1.x * v4 + at1.y * v5 + at1.z * v6 + at1.w * v7;
        w += __shfl_xor(w, 1);          // full 16-ch head logit (lane pair)
        float p = __expf(w);
        a0.x += p * f0; a0.y += p * f1; a0.z += p * f2; a0.w += p * f3;
        a1.x += p * f4; a1.y += p * f5; a1.z += p * f6; a1.w += p * f7;
        l += p;
    }
#pragma unroll
    for (int off = 16; off < 64; off <<= 1) {
        a0.x += __shfl_xor(a0.x, off); a0.y += __shfl_xor(a0.y, off);
        a0.z += __shfl_xor(a0.z, off); a0.w += __shfl_xor(a0.w, off);
        a1.x += __shfl_xor(a1.x, off); a1.y += __shfl_xor(a1.y, off);
        a1.z += __shfl_xor(a1.z, off); a1.w += __shfl_xor(a1.w, off);
        l += __shfl_xor(l, off);
    }
    if (quarter == 0) {
        float inv = 1.f / l;
        float4 b0 = ((const float4*)bias)[2 * q16];
        float4 b1 = ((const float4*)bias)[2 * q16 + 1];
        float4 o0, o1;
        o0.x = elu1(a0.x * inv + b0.x);
        o0.y = elu1(a0.y * inv + b0.y);
        o0.z = elu1(a0.z * inv + b0.z);
        o0.w = elu1(a0.w * inv + b0.w);
        o1.x = elu1(a1.x * inv + b1.x);
        o1.y = elu1(a1.y * inv + b1.y);
        o1.z = elu1(a1.z * inv + b1.z);
        o1.w = elu1(a1.w * inv + b1.w);
        // store bf16 row (halves write BW; gemm2 reads bf16 directly for MFMA)
        uint4 pk = make_uint4(pack2bf(o0.x, o0.y), pack2bf(o0.z, o0.w),
                              pack2bf(o1.x, o1.y), pack2bf(o1.z, o1.w));
        ((uint4*)(hb + (unsigned)d * DIN))[q16] = pk;
    }
}

// ---------- k4: layer-2 GEMM via MFMA: [xl2 | xr2] = hb @ [Wl2 | Wr2] ----------
__global__ __launch_bounds__(256) void gemm2(const unsigned short* __restrict__ hb,
                                             const unsigned short* __restrict__ Wb2,
                                             float* __restrict__ xl2, float* __restrict__ xr2) {
    __shared__ unsigned short As[GM][136];
    int t = threadIdx.x;
    int n0 = blockIdx.x * GM;
    {   // stage 32 bf16 rows (256B each): 8 threads/row x 2 uint4
        int row = t >> 3, s8 = t & 7;
        int nsrc = n0 + row < NN ? n0 + row : NN - 1;
        const uint4* src = (const uint4*)(hb + (size_t)nsrc * DIN);
        *(uint4*)&As[row][8 * s8]      = src[s8];
        *(uint4*)&As[row][8 * s8 + 64] = src[s8 + 8];
    }
    __syncthreads();
    int lane = t & 63, w = t >> 6;
    int m = lane & 15, quad = lane >> 4;
    int mt = w & 1, nt = w >> 1;
    f32x4 acc = (f32x4){0.f, 0.f, 0.f, 0.f};
#pragma unroll
    for (int ks = 0; ks < 4; ++ks) {
        int k = 32 * ks + 8 * quad;
        bf16x8 a = *(const bf16x8*)&As[16 * mt + m][k];
        bf16x8 b = *(const bf16x8*)(Wb2 + (size_t)(16 * nt + m) * 128 + k);
        acc = __builtin_amdgcn_mfma_f32_16x16x32_bf16(a, b, acc, 0, 0, 0);
    }
    float* __restrict__ dst = (nt == 0) ? xl2 : xr2;
#pragma unroll
    for (int r = 0; r < 4; ++r) {
        int node = n0 + 16 * mt + 4 * quad + r;
        if (node < NN) dst[(size_t)node * DOUT + m] = acc[r];
    }
}

// ---------- k5: layer-2 softmax + gather + bias + log_softmax (XCD-aligned mapping) ----------
__global__ __launch_bounds__(256) void l2_fused(const unsigned short* __restrict__ esrcPad,
                                                const int* __restrict__ cnt,
                                                const float* __restrict__ xl,
                                                const float* __restrict__ xr,
                                                const float* __restrict__ att,
                                                const float* __restrict__ bias,
                                                float* __restrict__ out) {
    int r = blockIdx.x & 7;
    int dq = (blockIdx.x >> 3) * 4 + (threadIdx.x >> 6);
    if (dq >= RANGE) return;        // wave-uniform
    int d = r * RANGE + dq;
    int lane = threadIdx.x & 63;
    int sl = lane >> 2;     // edge slot group 0..15
    int q = lane & 3;       // channel quad
    int rs = d * PAD;
    int re = rs + cnt[d];
    int last = re - 1;
    float4 xrq = ((const float4*)(xr + (unsigned)d * DOUT))[q];
    float4 atq = ((const float4*)att)[q];
    float4 acc = make_float4(0.f, 0.f, 0.f, 0.f);
    float l = 0.f;
    int slot = rs + sl;
    int c0 = slot < last ? slot : last;
    unsigned s0 = esrcPad[c0];
    for (; slot < re; slot += 16) {
        int c1 = slot + 16 < last ? slot + 16 : last;
        unsigned s1 = esrcPad[c1];
        float4 cur = ((const float4*)(xl + s0 * (unsigned)DOUT))[q];
        s0 = s1;
        float v0 = cur.x + xrq.x; v0 = fmaxf(v0, NEG * v0);
        float v1 = cur.y + xrq.y; v1 = fmaxf(v1, NEG * v1);
        float v2 = cur.z + xrq.z; v2 = fmaxf(v2, NEG * v2);
        float v3 = cur.w + xrq.w; v3 = fmaxf(v3, NEG * v3);
        float w = atq.x * v0 + atq.y * v1 + atq.z * v2 + atq.w * v3;
        w += __shfl_xor(w, 1);
        w += __shfl_xor(w, 2);          // full 16-ch logit
        float p = __expf(w);
        acc.x += p * cur.x; acc.y += p * cur.y;
        acc.z += p * cur.z; acc.w += p * cur.w;
        l += p;
    }
#pragma unroll
    for (int off = 4; off < 64; off <<= 1) {
        acc.x += __shfl_xor(acc.x, off);
        acc.y += __shfl_xor(acc.y, off);
        acc.z += __shfl_xor(acc.z, off);
        acc.w += __shfl_xor(acc.w, off);
        l += __shfl_xor(l, off);
    }
    float inv = 1.f / l;
    float4 b = ((const float4*)bias)[q];
    float4 v;
    v.x = acc.x * inv + b.x; v.y = acc.y * inv + b.y;
    v.z = acc.z * inv + b.z; v.w = acc.w * inv + b.w;
    float m = fmaxf(fmaxf(v.x, v.y), fmaxf(v.z, v.w));
    m = fmaxf(m, __shfl_xor(m, 1));
    m = fmaxf(m, __shfl_xor(m, 2));
    float es = __expf(v.x - m) + __expf(v.y - m) + __expf(v.z - m) + __expf(v.w - m);
    es += __shfl_xor(es, 1);
    es += __shfl_xor(es, 2);
    float lse = m + __logf(es);
    if (sl == 0) {
        ((float4*)(out + (size_t)d * DOUT))[q] = v;
        float4 ls;
        ls.x = v.x - lse; ls.y = v.y - lse; ls.z = v.z - lse; ls.w = v.w - lse;
        ((float4*)(out + (size_t)NN * DOUT + (size_t)d * DOUT))[q] = ls;
    }
}

extern "C" void kernel_launch(void* const* d_in, const int* in_sizes, int n_in,
                              void* d_out, int out_size, void* d_ws, size_t ws_size,
                              hipStream_t stream) {
    const float* x     = (const float*)d_in[0];
    const int*   ei    = (const int*)d_in[1];
    const float* Wl1   = (const float*)d_in[2];
    const float* Wr1   = (const float*)d_in[3];
    const float* att1  = (const float*)d_in[4];
    const float* bias1 = (const float*)d_in[5];
    const float* Wl2   = (const float*)d_in[6];
    const float* Wr2   = (const float*)d_in[7];
    const float* att2  = (const float*)d_in[8];
    const float* bias2 = (const float*)d_in[9];
    float* out = (float*)d_out;

    // ---- workspace layout (xr1 fp16) ----
    unsigned short* xr1 = (unsigned short*)d_ws;     // NN*128 fp16
    float* xl2    = (float*)(xr1 + (size_t)NN * DIN);// NN*16 fp32
    float* xr2    = xl2 + (size_t)NN * DOUT;         // NN*16 fp32
    unsigned short* xlb = (unsigned short*)(xr2 + (size_t)NN * DOUT); // NN*128 bf16
    unsigned short* hb  = xlb + (size_t)NN * DIN;    // NN*128 bf16
    unsigned short* Wb  = hb + (size_t)NN * DIN;     // 256*128 bf16
    unsigned short* Wb2 = Wb + 256 * 128;            // 32*128 bf16
    unsigned short* esrcPad = Wb2 + 32 * 128;        // NN*64 padded CSR (u16)
    int*   cnt    = (int*)(esrcPad + (size_t)NN * PAD);  // NN
    unsigned* bucket = (unsigned*)(cnt + NN);        // 8*BUCKCAP u32 (packed src<<16|dst)
    unsigned* bhead  = bucket + (size_t)8 * BUCKCAP; // 8

    const int B = 256;
    hipMemsetAsync(bhead, 0, 8 * sizeof(unsigned), stream);
    wcvt<<<144, B, 0, stream>>>(Wl1, Wr1, Wb, Wl2, Wr2, Wb2);
    bucket_gemm1<<<NB + ABLK + GB, B, 0, stream>>>(cnt, ei, bhead, bucket,
                                                   x, Wb, xlb, xr1);
    scatter_b<<<NPART * SCATB, B, 0, stream>>>(bucket, bhead, cnt, esrcPad);
    l1_fused<<<NPART * RB, B, 0, stream>>>(esrcPad, cnt, xlb, xr1, att1, bias1, hb);
    gemm2<<<GB, B, 0, stream>>>(hb, Wb2, xl2, xr2);
    l2_fused<<<NPART * RB, B, 0, stream>>>(esrcPad, cnt, xl2, xr2, att2, bias2, out);
}

// Round 12
// 223.301 us; speedup vs baseline: 1.0583x; 1.0583x over previous
//
#include <hip/hip_runtime.h>
#include <hip/hip_bf16.h>
#include <hip/hip_fp16.h>
#include <math.h>

#define NN 50000
#define EE 800000
#define DIN 128
#define HEADS 8
#define DH 16
#define DOUT 16
#define NEG 0.2f
#define GM 32       // nodes per GEMM block
#define GB ((NN + GM - 1) / GM)     // 1563 gemm1 blocks
#define NB ((NN + 255) / 256)       // 196 init blocks
#define ABLK ((EE / 4 + 255) / 256) // 782 bucket-append blocks
#define NPART 8                     // one dst-range per XCD (blockIdx%8 ~ XCD round-robin)
#define RANGE (NN / NPART)          // 6250 dst nodes per range
#define RB 1563                     // blocks per range in l1/l2 (ceil(RANGE/4))
#define SCATB 64                    // blocks per range in scatter path
#define BUCKCAP 110000              // per-range bucket capacity (mean 100k, sigma~296)
#define PAD 64      // padded CSR row slots; deg ~ Poisson(16), P(deg>=64) ~ 2e-18/node

typedef __attribute__((ext_vector_type(8))) short bf16x8;
typedef __attribute__((ext_vector_type(4))) float f32x4;
typedef __attribute__((ext_vector_type(4))) int i32x4;
typedef _Float16 h16x2 __attribute__((ext_vector_type(2)));

__device__ __forceinline__ unsigned pack2bf(float a, float b) {
    union { __hip_bfloat162 h; unsigned u; } c;
    c.h = __float22bfloat162_rn(make_float2(a, b));
    return c.u;
}
__device__ __forceinline__ unsigned short f2bf(float v) {
    union { __hip_bfloat16 h; unsigned short u; } c;
    c.h = __float2bfloat16(v);
    return c.u;
}
__device__ __forceinline__ unsigned short f2h(float v) {
    union { __half h; unsigned short u; } c;
    c.h = __float2half(v);
    return c.u;
}
__device__ __forceinline__ h16x2 u2h(unsigned u) { union { unsigned u; h16x2 h; } c; c.u = u; return c.h; }
__device__ __forceinline__ unsigned h2u(h16x2 h) { union { h16x2 h; unsigned u; } c; c.h = h; return c.u; }
// ELU negative branch: __expf(x)-1 (2 instr) instead of libm expm1f (~30 instr).
__device__ __forceinline__ float elu1(float x) { return x > 0.f ? x : __expf(x) - 1.f; }

// ---------- k1: cnt=1 (0..NB) || Wb1 cvt || Wb2 cvt || phase-A bucket append ----------
// bhead zeroed by hipMemsetAsync BEFORE this kernel (no in-kernel ordering dependence).
__global__ __launch_bounds__(256) void init_bucket(int* __restrict__ cnt,
                                                   const float* __restrict__ Wl,
                                                   const float* __restrict__ Wr,
                                                   unsigned short* __restrict__ Wb,
                                                   const float* __restrict__ Wl2,
                                                   const float* __restrict__ Wr2,
                                                   unsigned short* __restrict__ Wb2,
                                                   const int* __restrict__ ei,
                                                   unsigned* __restrict__ bhead,
                                                   unsigned* __restrict__ bucket) {
    int b = blockIdx.x, t = threadIdx.x;
    if (b < NB) {
        int i = b * 256 + t;
        if (i < NN) cnt[i] = 1;        // slot 0 = self-loop (written in scatter path)
        return;
    } else if (b < NB + 128) {
        int i = (b - NB) * 256 + t;   // 32768 entries
        int n = i >> 7, k = i & 127;
        float v = (n < 128) ? Wl[k * 128 + n] : Wr[k * 128 + (n - 128)];
        Wb[i] = f2bf(v);
        return;
    } else if (b < NB + 144) {
        int i = (b - NB - 128) * 256 + t;  // 4096 entries: Wb2[n][k], n in [0,32)
        int n = i >> 7, k = i & 127;
        float v = (n < 16) ? Wl2[k * 16 + n] : Wr2[k * 16 + (n - 16)];
        Wb2[i] = f2bf(v);
        return;
    }
    // ---- phase A: block-LDS 8-way bucket sort of 1024 edges, coalesced append ----
    __shared__ unsigned lrec[1024];
    __shared__ unsigned lcnt[8], loff[8], lpos[8], gbase[8];
    int ab = b - (NB + 144);
    int i = ab * 256 + t;
    bool valid = i < EE / 4;
    i32x4 ss, dd;
    unsigned bb[4];
    if (valid) {
        ss = __builtin_nontemporal_load(((const i32x4*)ei) + i);
        dd = __builtin_nontemporal_load(((const i32x4*)(ei + EE)) + i);
    }
    if (t < 8) { lcnt[t] = 0; lpos[t] = 0; }
    __syncthreads();
    if (valid) {
#pragma unroll
        for (int e = 0; e < 4; ++e) {
            bb[e] = (unsigned)dd[e] / RANGE;
            atomicAdd(&lcnt[bb[e]], 1u);
        }
    }
    __syncthreads();
    if (t == 0) {
        unsigned run = 0;
#pragma unroll
        for (int q = 0; q < 8; ++q) { loff[q] = run; run += lcnt[q]; }
    }
    if (t < 8 && lcnt[t] > 0) gbase[t] = atomicAdd(&bhead[t], lcnt[t]);
    __syncthreads();
    if (valid) {
#pragma unroll
        for (int e = 0; e < 4; ++e) {
            unsigned p = atomicAdd(&lpos[bb[e]], 1u);
            lrec[loff[bb[e]] + p] = ((unsigned)ss[e] << 16) | (unsigned)dd[e];
        }
    }
    __syncthreads();
    unsigned total = loff[7] + lcnt[7];
    for (unsigned j = t; j < total; j += 256) {
        unsigned q = 0;
        while (q < 7 && j >= loff[q + 1]) ++q;
        bucket[(size_t)q * BUCKCAP + gbase[q] + (j - loff[q])] = lrec[j];
    }
}

// ---------- k2: scatter (blocks 0..NPART*SCATB) || gemm1 MFMA (rest) ----------
// Scatter FIRST: its L2-local atomic stream (range r -> XCD r via blockIdx&7) starts at t=0
// and gemm1's dense MFMA work backfills. C-write via LDS transpose tile -> uint4 bursts.
// BOTH xlb and xr are fp16 now (xlb was bf16): same bytes, more mantissa, enables l1's
// packed-fp16 math.
__global__ __launch_bounds__(256) void scat_gemm1(const unsigned* __restrict__ bucket,
                                                  const unsigned* __restrict__ bhead,
                                                  int* __restrict__ cnt,
                                                  unsigned short* __restrict__ esrcPad,
                                                  const float* __restrict__ x,
                                                  const unsigned short* __restrict__ Wb,
                                                  unsigned short* __restrict__ xlb,
                                                  unsigned short* __restrict__ xr) {
    __shared__ unsigned short As[GM][136];   // staging tile (gemm1 path only)
    __shared__ unsigned short Cs[GM][264];   // C transpose tile (fp16), 16.9 KB
    int t = threadIdx.x;
    if (blockIdx.x < NPART * SCATB) {   // ---- scatter path ----
        int r = blockIdx.x & 7;
        int g = blockIdx.x >> 3;        // 0..SCATB-1
        if (g == 0) {                   // self-loops for this range
            for (int dq = t; dq < RANGE; dq += 256) {
                int d = r * RANGE + dq;
                esrcPad[(unsigned)d * PAD] = (unsigned short)d;
            }
        }
        unsigned n = bhead[r];
        for (unsigned i = (unsigned)g * 256 + t; i < n; i += SCATB * 256) {
            unsigned rec = __builtin_nontemporal_load(bucket + (size_t)r * BUCKCAP + i);
            unsigned s = rec >> 16, d = rec & 0xffffu;
            int p = atomicAdd(&cnt[d], 1);
            esrcPad[d * PAD + p] = (unsigned short)s;
        }
        return;
    }
    // ---- gemm1 path: 32 nodes x 256 cols, 4 waves; m89-verified 16x16x32 bf16 layouts ----
    int n0 = (blockIdx.x - NPART * SCATB) * GM;
    {   // stage: 32 rows x 128 ch fp32 -> bf16 LDS (nt: x is read-once)
        int row = t >> 3, seg = t & 7;
        int nsrc = n0 + row < NN ? n0 + row : NN - 1;   // clamp: safe read, store guarded
        const f32x4* xp = (const f32x4*)(x + (size_t)nsrc * DIN + 16 * seg);
        f32x4 v0 = __builtin_nontemporal_load(xp);
        f32x4 v1 = __builtin_nontemporal_load(xp + 1);
        f32x4 v2 = __builtin_nontemporal_load(xp + 2);
        f32x4 v3 = __builtin_nontemporal_load(xp + 3);
        uint4 p0 = make_uint4(pack2bf(v0[0], v0[1]), pack2bf(v0[2], v0[3]),
                              pack2bf(v1[0], v1[1]), pack2bf(v1[2], v1[3]));
        uint4 p1 = make_uint4(pack2bf(v2[0], v2[1]), pack2bf(v2[2], v2[3]),
                              pack2bf(v3[0], v3[1]), pack2bf(v3[2], v3[3]));
        *(uint4*)&As[row][16 * seg]     = p0;
        *(uint4*)&As[row][16 * seg + 8] = p1;
    }
    __syncthreads();
    int lane = t & 63, w = t >> 6;
    int m = lane & 15, quad = lane >> 4;
    f32x4 acc[2][4];
#pragma unroll
    for (int mt = 0; mt < 2; ++mt)
#pragma unroll
        for (int nt = 0; nt < 4; ++nt) acc[mt][nt] = (f32x4){0.f, 0.f, 0.f, 0.f};
#pragma unroll
    for (int ks = 0; ks < 4; ++ks) {
        int k = 32 * ks + 8 * quad;
        bf16x8 a0 = *(const bf16x8*)&As[m][k];
        bf16x8 a1 = *(const bf16x8*)&As[16 + m][k];
#pragma unroll
        for (int nt = 0; nt < 4; ++nt) {
            int n = 64 * w + 16 * nt + m;
            bf16x8 b = *(const bf16x8*)(Wb + (size_t)n * 128 + k);
            acc[0][nt] = __builtin_amdgcn_mfma_f32_16x16x32_bf16(a0, b, acc[0][nt], 0, 0, 0);
            acc[1][nt] = __builtin_amdgcn_mfma_f32_16x16x32_bf16(a1, b, acc[1][nt], 0, 0, 0);
        }
    }
    // C -> LDS transpose tile: fp16 for ALL cols (xlb fp16 | xr fp16)
#pragma unroll
    for (int mt = 0; mt < 2; ++mt) {
#pragma unroll
        for (int nt = 0; nt < 4; ++nt) {
            int col = 64 * w + 16 * nt + m;
            int rbase = 16 * mt + 4 * quad;
#pragma unroll
            for (int r = 0; r < 4; ++r) Cs[rbase + r][col] = f2h(acc[mt][nt][r]);
        }
    }
    __syncthreads();
    {   // coalesced write-out: thread (row, seg) moves 32B to xlb and 32B to xr
        int row = t >> 3, seg = t & 7;
        int grow = n0 + row;
        if (grow < NN) {
            uint4 a0 = *(uint4*)&Cs[row][16 * seg];
            uint4 a1 = *(uint4*)&Cs[row][16 * seg + 8];
            *(uint4*)(xlb + (unsigned)grow * DIN + 16 * seg)     = a0;
            *(uint4*)(xlb + (unsigned)grow * DIN + 16 * seg + 8) = a1;
            uint4 b0 = *(uint4*)&Cs[row][128 + 16 * seg];
            uint4 b1 = *(uint4*)&Cs[row][128 + 16 * seg + 8];
            *(uint4*)(xr + (unsigned)grow * DIN + 16 * seg)     = b0;
            *(uint4*)(xr + (unsigned)grow * DIN + 16 * seg + 8) = b1;
        }
    }
}

// ---------- k3: layer-1 fused, packed-fp16 hot loop ----------
// one wave per dst; quarter-wave per edge slot: 16 lanes x 8 fp16 channels.
// add + leaky-relu in v_pk_*_f16 (leaky via 0.6v+0.4|v|), logit via v_dot2_f32_f16,
// alpha*xl accumulation kept f32 for absmax safety.
__global__ __launch_bounds__(256) void l1_fused(const unsigned short* __restrict__ esrcPad,
                                                const int* __restrict__ cnt,
                                                const unsigned short* __restrict__ xlb,
                                                const unsigned short* __restrict__ xr,
                                                const float* __restrict__ att,
                                                const float* __restrict__ bias,
                                                unsigned short* __restrict__ hb) {
    int r = blockIdx.x & 7;
    int dq = (blockIdx.x >> 3) * 4 + (threadIdx.x >> 6);
    if (dq >= RANGE) return;        // wave-uniform (last block of each range)
    int d = r * RANGE + dq;
    int lane = threadIdx.x & 63;
    int quarter = lane >> 4;
    int q16 = lane & 15;        // channel octet [8*q16, 8*q16+8)
    int rs = d * PAD;
    int re = rs + cnt[d];       // cnt >= 1 (self-loop)
    int last = re - 1;
    uint4 xru = ((const uint4*)(xr + (unsigned)d * DIN))[q16];  // 8 fp16 ch (stay packed)
    h16x2 xh0 = u2h(xru.x), xh1 = u2h(xru.y), xh2 = u2h(xru.z), xh3 = u2h(xru.w);
    float4 at0 = ((const float4*)att)[2 * q16];
    float4 at1 = ((const float4*)att)[2 * q16 + 1];
    h16x2 ah0 = (h16x2){(_Float16)at0.x, (_Float16)at0.y};
    h16x2 ah1 = (h16x2){(_Float16)at0.z, (_Float16)at0.w};
    h16x2 ah2 = (h16x2){(_Float16)at1.x, (_Float16)at1.y};
    h16x2 ah3 = (h16x2){(_Float16)at1.z, (_Float16)at1.w};
    const h16x2 c06 = (h16x2){(_Float16)0.6f, (_Float16)0.6f};
    const h16x2 c04 = (h16x2){(_Float16)0.4f, (_Float16)0.4f};
    float4 a0 = make_float4(0.f, 0.f, 0.f, 0.f);
    float4 a1 = make_float4(0.f, 0.f, 0.f, 0.f);
    float l = 0.f;
    int slot = rs + quarter;
    int c0i = slot < last ? slot : last;
    unsigned s0 = esrcPad[c0i];
    int c1i = slot + 4 < last ? slot + 4 : last;
    unsigned s1 = esrcPad[c1i];
    uint4 row = ((const uint4*)(xlb + s0 * (unsigned)DIN))[q16];
    for (; slot < re; slot += 4) {
        uint4 cur = row;
        int c2i = slot + 8 < last ? slot + 8 : last;
        unsigned s2 = esrcPad[c2i];                                // 2 ahead
        row = ((const uint4*)(xlb + s1 * (unsigned)DIN))[q16];     // 1 ahead
        s1 = s2;
        h16x2 c0 = u2h(cur.x), c1 = u2h(cur.y), c2 = u2h(cur.z), c3 = u2h(cur.w);
        // v = xl + xr; leaky = 0.6v + 0.4|v|  (== max(v, 0.2v), 2e-4 rel bias)
        h16x2 v0 = c0 + xh0, v1 = c1 + xh1, v2 = c2 + xh2, v3 = c3 + xh3;
        h16x2 w0 = v0 * c06 + u2h(h2u(v0) & 0x7fff7fffu) * c04;
        h16x2 w1 = v1 * c06 + u2h(h2u(v1) & 0x7fff7fffu) * c04;
        h16x2 w2 = v2 * c06 + u2h(h2u(v2) & 0x7fff7fffu) * c04;
        h16x2 w3 = v3 * c06 + u2h(h2u(v3) & 0x7fff7fffu) * c04;
        float w = __builtin_amdgcn_fdot2(w0, ah0, 0.f, false);
        w = __builtin_amdgcn_fdot2(w1, ah1, w, false);
        w = __builtin_amdgcn_fdot2(w2, ah2, w, false);
        w = __builtin_amdgcn_fdot2(w3, ah3, w, false);
        w += __shfl_xor(w, 1);          // full 16-ch head logit (lane pair)
        float p = __expf(w);
        a0.x += p * (float)c0[0]; a0.y += p * (float)c0[1];
        a0.z += p * (float)c1[0]; a0.w += p * (float)c1[1];
        a1.x += p * (float)c2[0]; a1.y += p * (float)c2[1];
        a1.z += p * (float)c3[0]; a1.w += p * (float)c3[1];
        l += p;
    }
#pragma unroll
    for (int off = 16; off < 64; off <<= 1) {
        a0.x += __shfl_xor(a0.x, off); a0.y += __shfl_xor(a0.y, off);
        a0.z += __shfl_xor(a0.z, off); a0.w += __shfl_xor(a0.w, off);
        a1.x += __shfl_xor(a1.x, off); a1.y += __shfl_xor(a1.y, off);
        a1.z += __shfl_xor(a1.z, off); a1.w += __shfl_xor(a1.w, off);
        l += __shfl_xor(l, off);
    }
    if (quarter == 0) {
        float inv = 1.f / l;
        float4 b0 = ((const float4*)bias)[2 * q16];
        float4 b1 = ((const float4*)bias)[2 * q16 + 1];
        float4 o0, o1;
        o0.x = elu1(a0.x * inv + b0.x);
        o0.y = elu1(a0.y * inv + b0.y);
        o0.z = elu1(a0.z * inv + b0.z);
        o0.w = elu1(a0.w * inv + b0.w);
        o1.x = elu1(a1.x * inv + b1.x);
        o1.y = elu1(a1.y * inv + b1.y);
        o1.z = elu1(a1.z * inv + b1.z);
        o1.w = elu1(a1.w * inv + b1.w);
        // store bf16 row (gemm2 reads bf16 directly for MFMA)
        uint4 pk = make_uint4(pack2bf(o0.x, o0.y), pack2bf(o0.z, o0.w),
                              pack2bf(o1.x, o1.y), pack2bf(o1.z, o1.w));
        ((uint4*)(hb + (unsigned)d * DIN))[q16] = pk;
    }
}

// ---------- k4: layer-2 GEMM via MFMA: [xl2 | xr2] = hb @ [Wl2 | Wr2] ----------
__global__ __launch_bounds__(256) void gemm2(const unsigned short* __restrict__ hb,
                                             const unsigned short* __restrict__ Wb2,
                                             float* __restrict__ xl2, float* __restrict__ xr2) {
    __shared__ unsigned short As[GM][136];
    int t = threadIdx.x;
    int n0 = blockIdx.x * GM;
    {   // stage 32 bf16 rows (256B each): 8 threads/row x 2 uint4
        int row = t >> 3, s8 = t & 7;
        int nsrc = n0 + row < NN ? n0 + row : NN - 1;
        const uint4* src = (const uint4*)(hb + (size_t)nsrc * DIN);
        *(uint4*)&As[row][8 * s8]      = src[s8];
        *(uint4*)&As[row][8 * s8 + 64] = src[s8 + 8];
    }
    __syncthreads();
    int lane = t & 63, w = t >> 6;
    int m = lane & 15, quad = lane >> 4;
    int mt = w & 1, nt = w >> 1;
    f32x4 acc = (f32x4){0.f, 0.f, 0.f, 0.f};
#pragma unroll
    for (int ks = 0; ks < 4; ++ks) {
        int k = 32 * ks + 8 * quad;
        bf16x8 a = *(const bf16x8*)&As[16 * mt + m][k];
        bf16x8 b = *(const bf16x8*)(Wb2 + (size_t)(16 * nt + m) * 128 + k);
        acc = __builtin_amdgcn_mfma_f32_16x16x32_bf16(a, b, acc, 0, 0, 0);
    }
    float* __restrict__ dst = (nt == 0) ? xl2 : xr2;
#pragma unroll
    for (int r = 0; r < 4; ++r) {
        int node = n0 + 16 * mt + 4 * quad + r;
        if (node < NN) dst[(size_t)node * DOUT + m] = acc[r];
    }
}

// ---------- k5: layer-2 softmax + gather + bias + log_softmax (XCD-aligned mapping) ----------
__global__ __launch_bounds__(256) void l2_fused(const unsigned short* __restrict__ esrcPad,
                                                const int* __restrict__ cnt,
                                                const float* __restrict__ xl,
                                                const float* __restrict__ xr,
                                                const float* __restrict__ att,
                                                const float* __restrict__ bias,
                                                float* __restrict__ out) {
    int r = blockIdx.x & 7;
    int dq = (blockIdx.x >> 3) * 4 + (threadIdx.x >> 6);
    if (dq >= RANGE) return;        // wave-uniform
    int d = r * RANGE + dq;
    int lane = threadIdx.x & 63;
    int sl = lane >> 2;     // edge slot group 0..15
    int q = lane & 3;       // channel quad
    int rs = d * PAD;
    int re = rs + cnt[d];
    int last = re - 1;
    float4 xrq = ((const float4*)(xr + (unsigned)d * DOUT))[q];
    float4 atq = ((const float4*)att)[q];
    float4 acc = make_float4(0.f, 0.f, 0.f, 0.f);
    float l = 0.f;
    int slot = rs + sl;
    int c0 = slot < last ? slot : last;
    unsigned s0 = esrcPad[c0];
    for (; slot < re; slot += 16) {
        int c1 = slot + 16 < last ? slot + 16 : last;
        unsigned s1 = esrcPad[c1];
        float4 cur = ((const float4*)(xl + s0 * (unsigned)DOUT))[q];
        s0 = s1;
        float v0 = cur.x + xrq.x; v0 = fmaxf(v0, NEG * v0);
        float v1 = cur.y + xrq.y; v1 = fmaxf(v1, NEG * v1);
        float v2 = cur.z + xrq.z; v2 = fmaxf(v2, NEG * v2);
        float v3 = cur.w + xrq.w; v3 = fmaxf(v3, NEG * v3);
        float w = atq.x * v0 + atq.y * v1 + atq.z * v2 + atq.w * v3;
        w += __shfl_xor(w, 1);
        w += __shfl_xor(w, 2);          // full 16-ch logit
        float p = __expf(w);
        acc.x += p * cur.x; acc.y += p * cur.y;
        acc.z += p * cur.z; acc.w += p * cur.w;
        l += p;
    }
#pragma unroll
    for (int off = 4; off < 64; off <<= 1) {
        acc.x += __shfl_xor(acc.x, off);
        acc.y += __shfl_xor(acc.y, off);
        acc.z += __shfl_xor(acc.z, off);
        acc.w += __shfl_xor(acc.w, off);
        l += __shfl_xor(l, off);
    }
    float inv = 1.f / l;
    float4 b = ((const float4*)bias)[q];
    float4 v;
    v.x = acc.x * inv + b.x; v.y = acc.y * inv + b.y;
    v.z = acc.z * inv + b.z; v.w = acc.w * inv + b.w;
    float m = fmaxf(fmaxf(v.x, v.y), fmaxf(v.z, v.w));
    m = fmaxf(m, __shfl_xor(m, 1));
    m = fmaxf(m, __shfl_xor(m, 2));
    float es = __expf(v.x - m) + __expf(v.y - m) + __expf(v.z - m) + __expf(v.w - m);
    es += __shfl_xor(es, 1);
    es += __shfl_xor(es, 2);
    float lse = m + __logf(es);
    if (sl == 0) {
        ((float4*)(out + (size_t)d * DOUT))[q] = v;
        float4 ls;
        ls.x = v.x - lse; ls.y = v.y - lse; ls.z = v.z - lse; ls.w = v.w - lse;
        ((float4*)(out + (size_t)NN * DOUT + (size_t)d * DOUT))[q] = ls;
    }
}

extern "C" void kernel_launch(void* const* d_in, const int* in_sizes, int n_in,
                              void* d_out, int out_size, void* d_ws, size_t ws_size,
                              hipStream_t stream) {
    const float* x     = (const float*)d_in[0];
    const int*   ei    = (const int*)d_in[1];
    const float* Wl1   = (const float*)d_in[2];
    const float* Wr1   = (const float*)d_in[3];
    const float* att1  = (const float*)d_in[4];
    const float* bias1 = (const float*)d_in[5];
    const float* Wl2   = (const float*)d_in[6];
    const float* Wr2   = (const float*)d_in[7];
    const float* att2  = (const float*)d_in[8];
    const float* bias2 = (const float*)d_in[9];
    float* out = (float*)d_out;

    // ---- workspace layout (xr1 + xlb both fp16) ----
    unsigned short* xr1 = (unsigned short*)d_ws;     // NN*128 fp16
    float* xl2    = (float*)(xr1 + (size_t)NN * DIN);// NN*16 fp32
    float* xr2    = xl2 + (size_t)NN * DOUT;         // NN*16 fp32
    unsigned short* xlb = (unsigned short*)(xr2 + (size_t)NN * DOUT); // NN*128 fp16
    unsigned short* hb  = xlb + (size_t)NN * DIN;    // NN*128 bf16
    unsigned short* Wb  = hb + (size_t)NN * DIN;     // 256*128 bf16
    unsigned short* Wb2 = Wb + 256 * 128;            // 32*128 bf16
    unsigned short* esrcPad = Wb2 + 32 * 128;        // NN*64 padded CSR (u16)
    int*   cnt    = (int*)(esrcPad + (size_t)NN * PAD);  // NN
    unsigned* bucket = (unsigned*)(cnt + NN);        // 8*BUCKCAP u32 (packed src<<16|dst)
    unsigned* bhead  = bucket + (size_t)8 * BUCKCAP; // 8

    const int B = 256;
    hipMemsetAsync(bhead, 0, 8 * sizeof(unsigned), stream);
    init_bucket<<<NB + 144 + ABLK, B, 0, stream>>>(cnt, Wl1, Wr1, Wb, Wl2, Wr2, Wb2,
                                                   ei, bhead, bucket);
    scat_gemm1<<<NPART * SCATB + GB, B, 0, stream>>>(bucket, bhead, cnt, esrcPad,
                                                     x, Wb, xlb, xr1);
    l1_fused<<<NPART * RB, B, 0, stream>>>(esrcPad, cnt, xlb, xr1, att1, bias1, hb);
    gemm2<<<GB, B, 0, stream>>>(hb, Wb2, xl2, xr2);
    l2_fused<<<NPART * RB, B, 0, stream>>>(esrcPad, cnt, xl2, xr2, att2, bias2, out);
}